// Round 2
// baseline (1144.647 us; speedup 1.0000x reference)
//
#include <hip/hip_runtime.h>
#include <hip/hip_bf16.h>
#include <math.h>

// ---------------------------------------------------------------------------
// GenomicGNN: 2x GCN -> GAT(4 heads) -> mean-pool -> MLP head
// N=50000, E=800000 (+N self loops), F_IN=256, H=64, HEADS=4, G=64
// Strategy: build CSR (by dst) once per call, then all aggregations are
// per-destination GATHERS (register accumulation, no atomics, no zeroing).
// ---------------------------------------------------------------------------

__global__ void k_zero_i(int* __restrict__ p, int n) {
    int i = blockIdx.x * blockDim.x + threadIdx.x;
    if (i < n) p[i] = 0;
}

// in-degree histogram over real edges (self-loop folded in later as +1)
__global__ void k_count_deg(const int* __restrict__ dst, int* __restrict__ cnt, int E) {
    int e = blockIdx.x * blockDim.x + threadIdx.x;
    if (e < E) atomicAdd(&cnt[dst[e]], 1);
}

__global__ void k_dinv(const int* __restrict__ cnt, float* __restrict__ dinv, int N) {
    int n = blockIdx.x * blockDim.x + threadIdx.x;
    if (n < N) dinv[n] = rsqrtf((float)(cnt[n] + 1));   // +1 self loop, always > 0
}

// ---- 3-kernel exclusive scan of (cnt[n]+1) -> row_ptr (N <= 65536) ----
__global__ void k_scan1(const int* __restrict__ cnt, int* __restrict__ row,
                        int* __restrict__ bsum, int N) {
    __shared__ int lds[256];
    int tid = threadIdx.x;
    int i = blockIdx.x * 256 + tid;
    int v = (i < N) ? cnt[i] + 1 : 0;
    lds[tid] = v;
    __syncthreads();
    for (int off = 1; off < 256; off <<= 1) {
        int t = (tid >= off) ? lds[tid - off] : 0;
        __syncthreads();
        lds[tid] += t;
        __syncthreads();
    }
    if (i < N) row[i] = lds[tid] - v;           // exclusive within block
    if (tid == 255) bsum[blockIdx.x] = lds[255];
}

__global__ void k_scan2(int* __restrict__ bsum, int nb) {   // single block, nb<=256
    __shared__ int lds[256];
    int tid = threadIdx.x;
    int v = (tid < nb) ? bsum[tid] : 0;
    lds[tid] = v;
    __syncthreads();
    for (int off = 1; off < 256; off <<= 1) {
        int t = (tid >= off) ? lds[tid - off] : 0;
        __syncthreads();
        lds[tid] += t;
        __syncthreads();
    }
    if (tid < nb) bsum[tid] = lds[tid] - v;     // exclusive block offsets
}

__global__ void k_scan3(int* __restrict__ row, const int* __restrict__ bsum,
                        int* __restrict__ cursor, int N, int total) {
    int i = blockIdx.x * blockDim.x + threadIdx.x;
    if (i < N) {
        int r = row[i] + bsum[i >> 8];
        row[i] = r;
        cursor[i] = r;
    } else if (i == N) {
        row[N] = total;
    }
}

// bucket edges (+ self loops) into csr_src by dst
__global__ void k_place(const int* __restrict__ src, const int* __restrict__ dst,
                        int* __restrict__ cursor, int* __restrict__ csr, int E, int N) {
    int t = blockIdx.x * blockDim.x + threadIdx.x;
    if (t >= E + N) return;
    int d, v;
    if (t < E) { d = dst[t]; v = src[t]; } else { d = v = t - E; }
    int p = atomicAdd(&cursor[d], 1);
    csr[p] = v;
}

// ---- tiled GEMM: C[N,64] = A[N,K] @ B[K,64], 16 rows/block, A in LDS ----
template <int K>
__global__ void k_gemm_t(const float* __restrict__ A, const float* __restrict__ B,
                         float* __restrict__ C, int N) {
    __shared__ float lA[16 * K];
    int nb = blockIdx.x * 16, tid = threadIdx.x;
    for (int t = tid; t < 16 * K; t += 256) {
        int ni = nb + t / K;
        lA[t] = (ni < N) ? A[(long)ni * K + (t % K)] : 0.f;
    }
    __syncthreads();
    int j = tid & 63, slot = tid >> 6;          // 4 slots x 4 rows each
    float acc[4] = {0.f, 0.f, 0.f, 0.f};
#pragma unroll 4
    for (int k = 0; k < K; ++k) {
        float w = B[k * 64 + j];
#pragma unroll
        for (int i = 0; i < 4; ++i) acc[i] += lA[(slot + 4 * i) * K + k] * w;
    }
#pragma unroll
    for (int i = 0; i < 4; ++i) {
        int ni = nb + slot + 4 * i;
        if (ni < N) C[(long)ni * 64 + j] = acc[i];
    }
}

// GCN aggregation (gather): out[d] = relu(dinv[d] * sum_src in[src]*dinv[src] + b)
// one wave per node, lane = feature
__global__ void k_gcn_gather(const float* __restrict__ in, float* __restrict__ out,
                             const int* __restrict__ csr, const int* __restrict__ row,
                             const float* __restrict__ dinv, const float* __restrict__ b,
                             int N) {
    int node = blockIdx.x * 4 + (threadIdx.x >> 6);
    int l = threadIdx.x & 63;
    if (node >= N) return;
    int beg = row[node], end = row[node + 1];
    float acc = 0.f;
    for (int i = beg; i < end; ++i) {
        int s = csr[i];
        acc += in[(long)s * 64 + l] * dinv[s];
    }
    float v = acc * dinv[node] + b[l];
    out[(long)node * 64 + l] = v > 0.f ? v : 0.f;
}

// HH = R @ Wg (K=64, M=256), 8 rows/block, fused attention coefficients
__global__ void k_hh_attn(const float* __restrict__ Rm, const float* __restrict__ Wg,
                          const float* __restrict__ att_s, const float* __restrict__ att_d,
                          float* __restrict__ HH, float* __restrict__ a_s,
                          float* __restrict__ a_d, int N) {
    __shared__ float lA[8 * 64];
    int nb = blockIdx.x * 8, tid = threadIdx.x;
    for (int t = tid; t < 8 * 64; t += 256) {
        int ni = nb + t / 64;
        lA[t] = (ni < N) ? Rm[(long)ni * 64 + (t & 63)] : 0.f;
    }
    __syncthreads();
    int j = tid;
    float acc[8] = {0.f, 0.f, 0.f, 0.f, 0.f, 0.f, 0.f, 0.f};
#pragma unroll 4
    for (int k = 0; k < 64; ++k) {
        float w = Wg[k * 256 + j];
#pragma unroll
        for (int i = 0; i < 8; ++i) acc[i] += lA[i * 64 + k] * w;
    }
    float sj = att_s[j], dj = att_d[j];
    int h = j >> 6;
#pragma unroll
    for (int i = 0; i < 8; ++i) {
        int ni = nb + i;
        if (ni < N) {
            HH[(long)ni * 256 + j] = acc[i];
            float ps = acc[i] * sj, pd = acc[i] * dj;
            for (int off = 32; off; off >>= 1) {
                ps += __shfl_down(ps, off);
                pd += __shfl_down(pd, off);
            }
            if ((j & 63) == 0) {
                a_s[ni * 4 + h] = ps;
                a_d[ni * 4 + h] = pd;
            }
        }
    }
}

// GAT aggregation (gather): one wave per (node, head); online softmax in regs
__global__ void k_gat(const float* __restrict__ HH, const float* __restrict__ a_s,
                      const float* __restrict__ a_d, const int* __restrict__ csr,
                      const int* __restrict__ row, float* __restrict__ gat, int N) {
    int d = blockIdx.x;
    int h = threadIdx.x >> 6, l = threadIdx.x & 63;
    int beg = row[d], end = row[d + 1];
    float ad = a_d[d * 4 + h];
    // pass A: online softmax max+denom, lanes parallel over edges
    float m = -1e30f, den = 0.f;
    for (int c = beg; c < end; c += 64) {
        int i = c + l;
        float logit = -1e30f;
        if (i < end) {
            int s = csr[i];
            float v = a_s[s * 4 + h] + ad;
            logit = v > 0.f ? v : 0.2f * v;
        }
        float cm = logit;
        for (int off = 32; off; off >>= 1) cm = fmaxf(cm, __shfl_xor(cm, off));
        float nm = fmaxf(m, cm);
        float ex = expf(logit - nm);            // inactive lanes underflow to 0
        for (int off = 32; off; off >>= 1) ex += __shfl_xor(ex, off);
        den = den * expf(m - nm) + ex;
        m = nm;
    }
    float rden = 1.f / den;                      // den >= 1 (self loop)
    // pass B: weighted gather accumulate
    float acc = 0.f;
    for (int i = beg; i < end; ++i) {
        int s = csr[i];
        float v = a_s[s * 4 + h] + ad;
        v = v > 0.f ? v : 0.2f * v;
        float alpha = expf(v - m) * rden;
        acc += HH[(long)s * 256 + h * 64 + l] * alpha;
    }
    gat[(long)d * 256 + h * 64 + l] = acc;
}

__global__ void k_count_batch(const int* __restrict__ batch, int* __restrict__ cnt_g, int N) {
    int n = blockIdx.x * blockDim.x + threadIdx.x;
    if (n < N) atomicAdd(&cnt_g[batch[n]], 1);
}

// batch is sorted: graph g owns rows [sum cnt_g[0..g), +cnt_g[g])
__global__ void k_pool(const float* __restrict__ gat, const float* __restrict__ bg,
                       const int* __restrict__ cnt_g, float* __restrict__ pooled, int G) {
    int g = blockIdx.x, j = threadIdx.x;
    int off = 0;
    for (int i = 0; i < g; ++i) off += cnt_g[i];
    int c = cnt_g[g];
    float s = 0.f;
    for (int i = 0; i < c; ++i) s += gat[(long)(off + i) * 256 + j];
    pooled[g * 256 + j] = (s + (float)c * bg[j]) / fmaxf((float)c, 1.f);
}

// out[g] = relu(pooled @ Wf1 + bf1) @ Wf2 + bf2 ; one wave64 per graph
__global__ void k_head(const float* __restrict__ pooled, const float* __restrict__ Wf1,
                       const float* __restrict__ bf1, const float* __restrict__ Wf2,
                       const float* __restrict__ bf2, float* __restrict__ out, int G) {
    int g = blockIdx.x, t = threadIdx.x;
    float acc = bf1[t];
#pragma unroll 4
    for (int k = 0; k < 256; ++k) acc += pooled[g * 256 + k] * Wf1[k * 64 + t];
    float z = fmaxf(acc, 0.f);
    float p = z * Wf2[t];
    for (int off = 32; off; off >>= 1) p += __shfl_down(p, off);
    if (t == 0) out[g] = p + bf2[0];
}

extern "C" void kernel_launch(void* const* d_in, const int* in_sizes, int n_in,
                              void* d_out, int out_size, void* d_ws, size_t ws_size,
                              hipStream_t stream) {
    const float* x     = (const float*)d_in[0];
    const int*   eidx  = (const int*)d_in[1];
    const int*   batch = (const int*)d_in[2];
    const float* W1    = (const float*)d_in[3];
    const float* b1    = (const float*)d_in[4];
    const float* W2    = (const float*)d_in[5];
    const float* b2    = (const float*)d_in[6];
    const float* Wg    = (const float*)d_in[7];
    const float* att_s = (const float*)d_in[8];
    const float* att_d = (const float*)d_in[9];
    const float* bg    = (const float*)d_in[10];
    const float* Wf1   = (const float*)d_in[11];
    const float* bf1   = (const float*)d_in[12];
    const float* Wf2   = (const float*)d_in[13];
    const float* bf2   = (const float*)d_in[14];
    float* out = (float*)d_out;

    const int N = in_sizes[2];          // 50000
    const int E = in_sizes[1] / 2;      // 800000
    const int G = out_size;             // 64
    const int EN = E + N;
    const int* srcv = eidx;
    const int* dstv = eidx + E;
    (void)n_in; (void)ws_size;

    // ---- workspace layout ----
    int* cnt    = (int*)d_ws;                    // N   (in-degree, real edges)
    int* cnt_g  = cnt + N;                       // G
    int* rowp   = cnt_g + G;                     // N+1
    int* cursor = rowp + N + 1;                  // N+1
    int* bsum   = cursor + N + 1;                // 256
    int* csr    = bsum + 256;                    // E+N
    float* dinv = (float*)(csr + EN);            // N
    float* P    = dinv + N;                      // N*64 (gemm out; GAT overlays P..)
    float* Q    = P + (long)N * 64;              // N*64 (h1)
    float* R    = Q + (long)N * 64;              // N*64 (h2)
    float* GAT  = P;                             // N*256 (overlays P,Q,R,+pad)
    float* HH   = P + (long)N * 256;             // N*256
    float* a_s  = HH + (long)N * 256;            // N*4
    float* a_d  = a_s + (long)N * 4;             // N*4
    float* pooled = a_d + (long)N * 4;           // G*256

    const int nb = (N + 255) / 256;              // scan blocks (<=256)

    // ---- CSR build ----
    k_zero_i<<<(N + G + 255) / 256, 256, 0, stream>>>(cnt, N + G);
    k_count_deg<<<(E + 255) / 256, 256, 0, stream>>>(dstv, cnt, E);
    k_count_batch<<<(N + 255) / 256, 256, 0, stream>>>(batch, cnt_g, N);
    k_dinv<<<nb, 256, 0, stream>>>(cnt, dinv, N);
    k_scan1<<<nb, 256, 0, stream>>>(cnt, rowp, bsum, N);
    k_scan2<<<1, 256, 0, stream>>>(bsum, nb);
    k_scan3<<<(N + 256) / 256, 256, 0, stream>>>(rowp, bsum, cursor, N, EN);
    k_place<<<(EN + 255) / 256, 256, 0, stream>>>(srcv, dstv, cursor, csr, E, N);

    // ---- GCN layer 1: P = x@W1 ; Q = relu(gather(P) + b1) ----
    k_gemm_t<256><<<(N + 15) / 16, 256, 0, stream>>>(x, W1, P, N);
    k_gcn_gather<<<(N + 3) / 4, 256, 0, stream>>>(P, Q, csr, rowp, dinv, b1, N);

    // ---- GCN layer 2: P = Q@W2 ; R = relu(gather(P) + b2) ----
    k_gemm_t<64><<<(N + 15) / 16, 256, 0, stream>>>(Q, W2, P, N);
    k_gcn_gather<<<(N + 3) / 4, 256, 0, stream>>>(P, R, csr, rowp, dinv, b2, N);

    // ---- GAT: HH = R@Wg (+fused attn coeffs); gather with online softmax ----
    k_hh_attn<<<(N + 7) / 8, 256, 0, stream>>>(R, Wg, att_s, att_d, HH, a_s, a_d, N);
    k_gat<<<N, 256, 0, stream>>>(HH, a_s, a_d, csr, rowp, GAT, N);

    // ---- mean pool (sorted batch -> contiguous ranges) + MLP head ----
    k_pool<<<G, 256, 0, stream>>>(GAT, bg, cnt_g, pooled, G);
    k_head<<<G, 64, 0, stream>>>(pooled, Wf1, bf1, Wf2, bf2, out, G);
}

// Round 12
// 811.690 us; speedup vs baseline: 1.4102x; 1.4102x over previous
//
#include <hip/hip_runtime.h>
#include <hip/hip_bf16.h>
#include <math.h>

// ---------------------------------------------------------------------------
// GenomicGNN: 2x GCN -> GAT(4 heads) -> mean-pool -> MLP head
// N=50000, E=800000 (+N self loops), F_IN=256, H=64, HEADS=4, G=64
// CSR by dst built per call; all aggregations are per-destination gathers.
// Transform-last GAT: attention coeffs via folded 64x4 matrices
// (a_s = R @ w_s), aggregate R rows (256B/edge shared across heads), apply
// Wg AFTER mean-pooling. Deletes HH (N*256) gather buffer.
// ---------------------------------------------------------------------------

__global__ void k_zero_i(int* __restrict__ p, int n) {
    int i = blockIdx.x * blockDim.x + threadIdx.x;
    if (i < n) p[i] = 0;
}

__global__ void k_count_deg(const int* __restrict__ dst, int* __restrict__ cnt, int E) {
    int e = blockIdx.x * blockDim.x + threadIdx.x;
    if (e < E) atomicAdd(&cnt[dst[e]], 1);
}

__global__ void k_count_batch(const int* __restrict__ batch, int* __restrict__ cnt_g, int N) {
    int n = blockIdx.x * blockDim.x + threadIdx.x;
    if (n < N) atomicAdd(&cnt_g[batch[n]], 1);
}

__global__ void k_dinv(const int* __restrict__ cnt, float* __restrict__ dinv, int N) {
    int n = blockIdx.x * blockDim.x + threadIdx.x;
    if (n < N) dinv[n] = rsqrtf((float)(cnt[n] + 1));   // +1 self loop, > 0
}

// ---- 3-kernel exclusive scan of (cnt[n]+1) -> row_ptr (N <= 65536) ----
__global__ void k_scan1(const int* __restrict__ cnt, int* __restrict__ row,
                        int* __restrict__ bsum, int N) {
    __shared__ int lds[256];
    int tid = threadIdx.x;
    int i = blockIdx.x * 256 + tid;
    int v = (i < N) ? cnt[i] + 1 : 0;
    lds[tid] = v;
    __syncthreads();
    for (int off = 1; off < 256; off <<= 1) {
        int t = (tid >= off) ? lds[tid - off] : 0;
        __syncthreads();
        lds[tid] += t;
        __syncthreads();
    }
    if (i < N) row[i] = lds[tid] - v;
    if (tid == 255) bsum[blockIdx.x] = lds[255];
}

__global__ void k_scan2(int* __restrict__ bsum, int nb) {   // 1 block, nb<=256
    __shared__ int lds[256];
    int tid = threadIdx.x;
    int v = (tid < nb) ? bsum[tid] : 0;
    lds[tid] = v;
    __syncthreads();
    for (int off = 1; off < 256; off <<= 1) {
        int t = (tid >= off) ? lds[tid - off] : 0;
        __syncthreads();
        lds[tid] += t;
        __syncthreads();
    }
    if (tid < nb) bsum[tid] = lds[tid] - v;
}

__global__ void k_scan3(int* __restrict__ row, const int* __restrict__ bsum,
                        int* __restrict__ cursor, int N, int total) {
    int i = blockIdx.x * blockDim.x + threadIdx.x;
    if (i < N) {
        int r = row[i] + bsum[i >> 8];
        row[i] = r;
        cursor[i] = r;
    } else if (i == N) {
        row[N] = total;
    }
}

__global__ void k_place(const int* __restrict__ src, const int* __restrict__ dst,
                        int* __restrict__ cursor, int* __restrict__ csr, int E, int N) {
    int t = blockIdx.x * blockDim.x + threadIdx.x;
    if (t >= E + N) return;
    int d, v;
    if (t < E) { d = dst[t]; v = src[t]; } else { d = v = t - E; }
    int p = atomicAdd(&cursor[d], 1);
    csr[p] = v;
}

// fold Wg + att into w_s,w_d [64][4]: w_s[k*4+h] = sum_c Wg[k,h*64+c]*att_s[h,c]
__global__ void k_fold_att(const float* __restrict__ Wg, const float* __restrict__ att_s,
                           const float* __restrict__ att_d, float* __restrict__ w_s,
                           float* __restrict__ w_d) {
    int tid = threadIdx.x;            // 256 = 64 k * 4 h
    int k = tid >> 2, h = tid & 3;
    float as = 0.f, ad = 0.f;
    const float* wrow = Wg + k * 256 + h * 64;
    const float* s = att_s + h * 64;
    const float* d = att_d + h * 64;
#pragma unroll 4
    for (int c = 0; c < 64; ++c) {
        float w = wrow[c];
        as += w * s[c];
        ad += w * d[c];
    }
    w_s[tid] = as;
    w_d[tid] = ad;
}

// ---- tiled GEMM: C[N,64] = (A[N,K] @ B[K,64]) * scale[n] ----
template <int K>
__global__ void k_gemm_t(const float* __restrict__ A, const float* __restrict__ B,
                         float* __restrict__ C, int N, const float* __restrict__ scale) {
    __shared__ float lA[16 * K];
    int nb = blockIdx.x * 16, tid = threadIdx.x;
    for (int t = tid; t < 16 * K; t += 256) {
        int ni = nb + t / K;
        lA[t] = (ni < N) ? A[(long)ni * K + (t % K)] : 0.f;
    }
    __syncthreads();
    int j = tid & 63, slot = tid >> 6;          // 4 slots x 4 rows each
    float acc[4] = {0.f, 0.f, 0.f, 0.f};
#pragma unroll 4
    for (int k = 0; k < K; ++k) {
        float w = B[k * 64 + j];
#pragma unroll
        for (int i = 0; i < 4; ++i) acc[i] += lA[(slot + 4 * i) * K + k] * w;
    }
#pragma unroll
    for (int i = 0; i < 4; ++i) {
        int ni = nb + slot + 4 * i;
        if (ni < N) C[(long)ni * 64 + j] = acc[i] * scale[ni];
    }
}

// GCN aggregation (gather): out[d] = relu(dinv[d]*sum_s in[s] + b)
// (in rows prescaled by dinv[s]); one wave per node, lane = feature.
// ATTN=1: also emit a_s/a_d = out_row @ w_s/w_d (8 shfl-reductions).
template <int ATTN>
__global__ void k_gcn_gather(const float* __restrict__ in, float* __restrict__ out,
                             const int* __restrict__ csr, const int* __restrict__ row,
                             const float* __restrict__ dinv, const float* __restrict__ b,
                             const float* __restrict__ w_s, const float* __restrict__ w_d,
                             float* __restrict__ a_s, float* __restrict__ a_d, int N) {
    int node = blockIdx.x * 4 + (threadIdx.x >> 6);
    int l = threadIdx.x & 63;
    if (node >= N) return;
    int beg = row[node], end = row[node + 1];
    float acc = 0.f;
    for (int c = beg; c < end; c += 64) {
        int cc = end - c; if (cc > 64) cc = 64;
        int s = (l < cc) ? csr[c + l] : 0;      // coalesced chunk load
        for (int j = 0; j < cc; ++j) {
            int sj = __shfl(s, j);
            acc += in[(long)sj * 64 + l];
        }
    }
    float v = fmaxf(acc * dinv[node] + b[l], 0.f);
    out[(long)node * 64 + l] = v;
    if (ATTN) {
        float ps0 = v * w_s[l * 4 + 0], ps1 = v * w_s[l * 4 + 1];
        float ps2 = v * w_s[l * 4 + 2], ps3 = v * w_s[l * 4 + 3];
        float pd0 = v * w_d[l * 4 + 0], pd1 = v * w_d[l * 4 + 1];
        float pd2 = v * w_d[l * 4 + 2], pd3 = v * w_d[l * 4 + 3];
#pragma unroll
        for (int off = 32; off; off >>= 1) {
            ps0 += __shfl_xor(ps0, off); ps1 += __shfl_xor(ps1, off);
            ps2 += __shfl_xor(ps2, off); ps3 += __shfl_xor(ps3, off);
            pd0 += __shfl_xor(pd0, off); pd1 += __shfl_xor(pd1, off);
            pd2 += __shfl_xor(pd2, off); pd3 += __shfl_xor(pd3, off);
        }
        if (l == 0) {
            a_s[node * 4 + 0] = ps0; a_s[node * 4 + 1] = ps1;
            a_s[node * 4 + 2] = ps2; a_s[node * 4 + 3] = ps3;
            a_d[node * 4 + 0] = pd0; a_d[node * 4 + 1] = pd1;
            a_d[node * 4 + 2] = pd2; a_d[node * 4 + 3] = pd3;
        }
    }
}

// GAT pre-transform aggregate: AGG[d,h,k] = sum_s alpha_{s,d,h} * R[s,k].
// One block per node, wave = head; single-pass online softmax; all 4 waves
// gather the SAME R row (L1/L2 reuse; R is only 12.8 MB).
__global__ void k_gat_agg(const float* __restrict__ R, const float* __restrict__ a_s,
                          const float* __restrict__ a_d, const int* __restrict__ csr,
                          const int* __restrict__ row, float* __restrict__ AGG, int N) {
    int d = blockIdx.x;
    int h = threadIdx.x >> 6, l = threadIdx.x & 63;
    int beg = row[d], end = row[d + 1];
    float ad = a_d[d * 4 + h];
    const float* Rl = R + l;
    float m = -1e30f, den = 0.f, acc = 0.f;
    for (int c = beg; c < end; c += 64) {
        int cc = end - c; if (cc > 64) cc = 64;
        int i = c + l;
        int s = csr[(i < end) ? i : (end - 1)];
        float v = a_s[s * 4 + h] + ad;
        v = v > 0.f ? v : 0.2f * v;
        float logit = (l < cc) ? v : -1e30f;
        float cm = logit;
#pragma unroll
        for (int off = 32; off; off >>= 1) cm = fmaxf(cm, __shfl_xor(cm, off));
        float nm = fmaxf(m, cm);
        float scale = __expf(m - nm);           // 0 on first chunk
        float p = __expf(logit - nm);           // 0 for invalid lanes
        acc *= scale;
        den = den * scale + p;                  // lane-local denom
        m = nm;
        for (int j = 0; j < cc; ++j) {
            float pj = __shfl(p, j);
            int sj = __shfl(s, j);
            acc += Rl[(long)sj * 64] * pj;
        }
    }
#pragma unroll
    for (int off = 32; off; off >>= 1) den += __shfl_xor(den, off);
    AGG[(long)d * 256 + h * 64 + l] = acc / den;    // den >= 1 (self loop)
}

// run-length mean-pool partial sums: 64 nodes/block, flush on graph change
__global__ void k_pool_part(const float* __restrict__ AGG, const int* __restrict__ batch,
                            float* __restrict__ psum, int N) {
    int base = blockIdx.x * 64;
    int j = threadIdx.x;
    int nEnd = base + 64; if (nEnd > N) nEnd = N;
    if (base >= N) return;
    float acc = 0.f;
    int g = batch[base];
    for (int n = base; n < nEnd; ++n) {
        int gn = batch[n];
        if (gn != g) {
            atomicAdd(&psum[g * 256 + j], acc);
            acc = 0.f; g = gn;
        }
        acc += AGG[(long)n * 256 + j];
    }
    atomicAdd(&psum[g * 256 + j], acc);
}

// per graph: pooled[j] = ((psum @ Wg)[j] + cnt*bg[j]) / max(cnt,1), then MLP:
// out[g] = relu(pooled @ Wf1 + bf1) @ Wf2 + bf2
__global__ void k_head(const float* __restrict__ psum, const int* __restrict__ cnt_g,
                       const float* __restrict__ Wg, const float* __restrict__ bg,
                       const float* __restrict__ Wf1, const float* __restrict__ bf1,
                       const float* __restrict__ Wf2, const float* __restrict__ bf2,
                       float* __restrict__ out, int G) {
    __shared__ float rowl[256], pooled[256];
    int g = blockIdx.x, tid = threadIdx.x;
    rowl[tid] = psum[g * 256 + tid];
    __syncthreads();
    float cnt = (float)cnt_g[g];
    float inv = 1.f / fmaxf(cnt, 1.f);
    int h = tid >> 6;
    float s = 0.f;
    const float* arow = rowl + h * 64;
#pragma unroll 4
    for (int k = 0; k < 64; ++k) s += arow[k] * Wg[k * 256 + tid];
    pooled[tid] = (s + cnt * bg[tid]) * inv;
    __syncthreads();
    if (tid < 64) {
        float acc = bf1[tid];
#pragma unroll 4
        for (int k = 0; k < 256; ++k) acc += pooled[k] * Wf1[k * 64 + tid];
        float z = fmaxf(acc, 0.f);
        float p = z * Wf2[tid];
#pragma unroll
        for (int off = 32; off; off >>= 1) p += __shfl_down(p, off);
        if (tid == 0) out[g] = p + bf2[0];
    }
}

extern "C" void kernel_launch(void* const* d_in, const int* in_sizes, int n_in,
                              void* d_out, int out_size, void* d_ws, size_t ws_size,
                              hipStream_t stream) {
    const float* x     = (const float*)d_in[0];
    const int*   eidx  = (const int*)d_in[1];
    const int*   batch = (const int*)d_in[2];
    const float* W1    = (const float*)d_in[3];
    const float* b1    = (const float*)d_in[4];
    const float* W2    = (const float*)d_in[5];
    const float* b2    = (const float*)d_in[6];
    const float* Wg    = (const float*)d_in[7];
    const float* att_s = (const float*)d_in[8];
    const float* att_d = (const float*)d_in[9];
    const float* bg    = (const float*)d_in[10];
    const float* Wf1   = (const float*)d_in[11];
    const float* bf1   = (const float*)d_in[12];
    const float* Wf2   = (const float*)d_in[13];
    const float* bf2   = (const float*)d_in[14];
    float* out = (float*)d_out;

    const int N = in_sizes[2];          // 50000
    const int E = in_sizes[1] / 2;      // 800000
    const int G = out_size;             // 64
    const int EN = E + N;
    const int* srcv = eidx;
    const int* dstv = eidx + E;
    (void)n_in; (void)ws_size;

    // ---- workspace layout ----
    int* cnt      = (int*)d_ws;                  // N
    int* cnt_g    = cnt + N;                     // G
    float* psum   = (float*)(cnt_g + G);         // G*256 (zeroed with cnt/cnt_g)
    int* rowp     = (int*)(psum + (long)G * 256);// N+1
    int* cursor   = rowp + N + 1;                // N+1
    int* bsum     = cursor + N + 1;              // 256
    int* csr      = bsum + 256;                  // E+N
    float* dinv   = (float*)(csr + EN);          // N
    float* w_s    = dinv + N;                    // 256 (folded att_src)
    float* w_d    = w_s + 256;                   // 256
    float* a_s    = w_d + 256;                   // N*4
    float* a_d    = a_s + (long)N * 4;           // N*4
    float* P      = a_d + (long)N * 4;           // N*64
    float* Q      = P + (long)N * 64;            // N*64
    float* R      = Q + (long)N * 64;            // N*64
    float* AGG    = R + (long)N * 64;            // N*256

    const int nb = (N + 255) / 256;              // scan blocks (<=256)
    const int zn = N + G + G * 256;              // cnt + cnt_g + psum

    // ---- CSR build + degrees + batch counts + folded attention ----
    k_zero_i<<<(zn + 255) / 256, 256, 0, stream>>>(cnt, zn);
    k_count_deg<<<(E + 255) / 256, 256, 0, stream>>>(dstv, cnt, E);
    k_count_batch<<<(N + 255) / 256, 256, 0, stream>>>(batch, cnt_g, N);
    k_fold_att<<<1, 256, 0, stream>>>(Wg, att_s, att_d, w_s, w_d);
    k_dinv<<<nb, 256, 0, stream>>>(cnt, dinv, N);
    k_scan1<<<nb, 256, 0, stream>>>(cnt, rowp, bsum, N);
    k_scan2<<<1, 256, 0, stream>>>(bsum, nb);
    k_scan3<<<(N + 256) / 256, 256, 0, stream>>>(rowp, bsum, cursor, N, EN);
    k_place<<<(EN + 255) / 256, 256, 0, stream>>>(srcv, dstv, cursor, csr, E, N);

    // ---- GCN layer 1: P = (x@W1)*dinv ; Q = relu(dinv*gather(P) + b1) ----
    k_gemm_t<256><<<(N + 15) / 16, 256, 0, stream>>>(x, W1, P, N, dinv);
    k_gcn_gather<0><<<(N + 3) / 4, 256, 0, stream>>>(P, Q, csr, rowp, dinv, b1,
                                                     nullptr, nullptr, nullptr, nullptr, N);

    // ---- GCN layer 2 (+ attn coeff epilogue): R = relu(...), a_s/a_d = R@w ----
    k_gemm_t<64><<<(N + 15) / 16, 256, 0, stream>>>(Q, W2, P, N, dinv);
    k_gcn_gather<1><<<(N + 3) / 4, 256, 0, stream>>>(P, R, csr, rowp, dinv, b2,
                                                     w_s, w_d, a_s, a_d, N);

    // ---- GAT aggregate (transform-last): AGG = softmax-weighted gather of R ----
    k_gat_agg<<<N, 256, 0, stream>>>(R, a_s, a_d, csr, rowp, AGG, N);

    // ---- mean pool AGG (run-length) ; head applies Wg + bg + MLP ----
    k_pool_part<<<(N + 63) / 64, 256, 0, stream>>>(AGG, batch, psum, N);
    k_head<<<G, 256, 0, stream>>>(psum, cnt_g, Wg, bg, Wf1, bf1, Wf2, bf2, out, G);
}